// Round 10
// baseline (68.317 us; speedup 1.0000x reference)
//
#include <hip/hip_runtime.h>
#include <math.h>

#define NNODES 50000
#define NEDGES 1600000
#define BINSZ 128                  // nodes per bin (bin = c >> 7)
#define NBINS 391                  // ceil(50000/128)
#define NBLK 500                   // binning blocks
#define EPB (NEDGES / NBLK)        // 3200 edges per binning block
#define FCAP 32                    // slots per (bin, block) fragment; Poisson(8.18), P(>32)~6e-10/frag
#define BCAP 4608                  // per-bin edge capacity (mean 4092, +8 sigma)
#define SCALE 0.17677669529663687f // 1/sqrt(32)

// Constant table C[] (LDS, 180 floats), built redundantly per block (5.7k MACs):
//   A[h][a][b]  : 0   + h*16 + a*4 + b   (Wq_h^T Wk_h)
//   U[h][b]     : 64  + h*4 + b          (bq_h^T Wk_h)   pairs with x[c]
//   V[h][a]     : 80  + h*4 + a          (Wq_h^T bk_h)   pairs with x[r]
//   W0[h]       : 96  + h                (bq_h . bk_h)
//   M[h][o][a]  : 100 + h*16 + o*4 + a   (Wo[o,hslice] . Wv_h[:,a])
//   N[h][o]     : 164 + h*4 + o          (Wo[o,hslice] . bv_h)
__device__ __forceinline__ void compute_C_entry(int t,
        const float* Wq, const float* bq, const float* Wk, const float* bk,
        const float* Wv, const float* bv, const float* Wo, float* C_lds) {
    if (t < 64) {
        int h = t >> 4, a = (t >> 2) & 3, b = t & 3;
        float s = 0.f;
        for (int k = 0; k < 32; k++) s += Wq[(h * 32 + k) * 4 + a] * Wk[(h * 32 + k) * 4 + b];
        C_lds[t] = s;
    } else if (t < 80) {
        int h = (t - 64) >> 2, b = (t - 64) & 3;
        float s = 0.f;
        for (int k = 0; k < 32; k++) s += bq[h * 32 + k] * Wk[(h * 32 + k) * 4 + b];
        C_lds[t] = s;
    } else if (t < 96) {
        int h = (t - 80) >> 2, a = (t - 80) & 3;
        float s = 0.f;
        for (int k = 0; k < 32; k++) s += Wq[(h * 32 + k) * 4 + a] * bk[h * 32 + k];
        C_lds[t] = s;
    } else if (t < 100) {
        int h = t - 96;
        float s = 0.f;
        for (int k = 0; k < 32; k++) s += bq[h * 32 + k] * bk[h * 32 + k];
        C_lds[t] = s;
    } else if (t < 164) {
        int i = t - 100;
        int h = i >> 4, o = (i >> 2) & 3, a = i & 3;
        float s = 0.f;
        for (int k = 0; k < 32; k++) s += Wo[o * 128 + h * 32 + k] * Wv[(h * 32 + k) * 4 + a];
        C_lds[t] = s;
    } else if (t < 180) {
        int i = t - 164;
        int h = i >> 2, o = i & 3;
        float s = 0.f;
        for (int k = 0; k < 32; k++) s += Wo[o * 128 + h * 32 + k] * bv[h * 32 + k];
        C_lds[t] = s;
    }
}

// Zero-coordination binning: each block owns a private FCAP-slot fragment per
// bin. Edges packed as (c<<16)|(r+1); 0 = empty sentinel. No global atomics,
// no cross-block shared cache lines (fragment = 128 B = 2 exclusive lines).
__global__ __launch_bounds__(256) void k_binA(const int* __restrict__ ei,
                                              unsigned* __restrict__ binned) {
    __shared__ int cnt[NBINS];
    int t = threadIdx.x;
    int blk = blockIdx.x;
    for (int i = t; i < NBINS; i += 256) cnt[i] = 0;
    __syncthreads();
    int e0 = blk * EPB;
    unsigned* frag = binned + (size_t)blk * FCAP;  // + bin * NBLK*FCAP
    for (int i = t; i < EPB; i += 256) {
        int e = e0 + i;
        int r = ei[e];
        int c = ei[NEDGES + e];
        int b = c >> 7;
        int off = atomicAdd(&cnt[b], 1);
        if (off < FCAP)
            frag[(size_t)b * (NBLK * FCAP) + off] = ((unsigned)c << 16) | (unsigned)(r + 1);
    }
    __syncthreads();
    // fill unused slots with sentinel 0 (block-private lines, fire-and-forget)
    for (int b = t; b < NBINS; b += 256) {
        int n = cnt[b]; if (n > FCAP) n = FCAP;
        unsigned* fp = frag + (size_t)b * (NBLK * FCAP);
        for (int j = n; j < FCAP; j++) fp[j] = 0u;
    }
}

// One block per 128-node bin: scan the bin's contiguous 500*32-slot region
// (uint4), compact valid edges to LDS, counting-sort by local node (int LDS
// atomics only), then 2 lanes/node accumulate y_h/S_h in registers.
__global__ __launch_bounds__(256) void k_accum(
        const unsigned* __restrict__ binned, const float* __restrict__ x,
        const float* __restrict__ Wq, const float* __restrict__ bq,
        const float* __restrict__ Wk, const float* __restrict__ bk,
        const float* __restrict__ Wv, const float* __restrict__ bv,
        const float* __restrict__ Wo,
        float* __restrict__ acc, float* __restrict__ pS) {
    __shared__ float Cl[192];
    __shared__ float pe[BINSZ][20];
    __shared__ unsigned raw[BCAP];
    __shared__ unsigned short srt[BCAP];
    __shared__ int hist[BINSZ];
    __shared__ int ofs[BINSZ];
    __shared__ int nv;
    __shared__ float sw[4][4];
    int bin = blockIdx.x;
    int t = threadIdx.x;
    int base = bin << 7;
    compute_C_entry(t, Wq, bq, Wk, bk, Wv, bv, Wo, Cl);
    if (t < BINSZ) hist[t] = 0;
    if (t == 0) nv = 0;
    __syncthreads();
    // per-node score coefficients g[16], e[4]
    if (t < BINSZ) {
        int node = base + t;
        if (node < NNODES) {
            float4 xv = ((const float4*)x)[node];
            float pr[20];
#pragma unroll
            for (int h = 0; h < 4; h++) {
#pragma unroll
                for (int a = 0; a < 4; a++) {
                    float g = Cl[80 + h * 4 + a]
                            + Cl[h * 16 + a * 4 + 0] * xv.x + Cl[h * 16 + a * 4 + 1] * xv.y
                            + Cl[h * 16 + a * 4 + 2] * xv.z + Cl[h * 16 + a * 4 + 3] * xv.w;
                    pr[h * 4 + a] = g * SCALE;
                }
                float e = Cl[96 + h]
                        + Cl[64 + h * 4 + 0] * xv.x + Cl[64 + h * 4 + 1] * xv.y
                        + Cl[64 + h * 4 + 2] * xv.z + Cl[64 + h * 4 + 3] * xv.w;
                pr[16 + h] = e * SCALE;
            }
#pragma unroll
            for (int q = 0; q < 5; q++) ((float4*)pe[t])[q] = ((const float4*)pr)[q];
        }
    }
    // scan fragment region (coalesced uint4), compact + histogram
    const uint4* reg = (const uint4*)(binned + (size_t)bin * (NBLK * FCAP));
    for (int i = t; i < NBLK * FCAP / 4; i += 256) {
        uint4 v4 = reg[i];
#pragma unroll
        for (int q = 0; q < 4; q++) {
            unsigned v = (q == 0) ? v4.x : (q == 1) ? v4.y : (q == 2) ? v4.z : v4.w;
            if (v != 0u) {
                int pos = atomicAdd(&nv, 1);
                if (pos < BCAP) {
                    raw[pos] = v;
                    atomicAdd(&hist[(int)(v >> 16) - base], 1);
                }
            }
        }
    }
    __syncthreads();
    // exclusive prefix over 128 counters (wave 0, 2 counters/lane)
    if (t < 64) {
        int h0 = hist[2 * t], h1 = hist[2 * t + 1];
        int pair = h0 + h1;
        int p = pair;
#pragma unroll
        for (int off = 1; off < 64; off <<= 1) {
            int u = __shfl_up(p, off, 64);
            if (t >= off) p += u;
        }
        int excl = p - pair;
        hist[2 * t] = excl; hist[2 * t + 1] = excl + h0;
        ofs[2 * t] = excl;  ofs[2 * t + 1] = excl + h0;
    }
    __syncthreads();
    int nval = nv < BCAP ? nv : BCAP;
    // scatter into per-node contiguous segments
    for (int i = t; i < nval; i += 256) {
        unsigned v = raw[i];
        int lc = (int)(v >> 16) - base;
        int pos = atomicAdd(&ofs[lc], 1);
        srt[pos] = (unsigned short)(v & 0xFFFFu);   // r+1
    }
    __syncthreads();
    // accumulate: 2 lanes per node, registers only
    int nl = t >> 1;
    int sub = t & 1;
    int node = base + nl;
    int sBeg = hist[nl], sEnd = ofs[nl];
    float4 g0 = ((const float4*)pe[nl])[0];
    float4 g1 = ((const float4*)pe[nl])[1];
    float4 g2 = ((const float4*)pe[nl])[2];
    float4 g3 = ((const float4*)pe[nl])[3];
    float4 eh = ((const float4*)pe[nl])[4];
    float S0 = 0.f, S1 = 0.f, S2 = 0.f, S3 = 0.f;
    float4 y0 = {0, 0, 0, 0}, y1 = y0, y2 = y0, y3 = y0;
    for (int i = sBeg + sub; i < sEnd; i += 2) {
        int r = (int)srt[i] - 1;
        float4 xv = ((const float4*)x)[r];
        float p0 = __expf(xv.x * g0.x + xv.y * g0.y + xv.z * g0.z + xv.w * g0.w + eh.x);
        float p1 = __expf(xv.x * g1.x + xv.y * g1.y + xv.z * g1.z + xv.w * g1.w + eh.y);
        float p2 = __expf(xv.x * g2.x + xv.y * g2.y + xv.z * g2.z + xv.w * g2.w + eh.z);
        float p3 = __expf(xv.x * g3.x + xv.y * g3.y + xv.z * g3.z + xv.w * g3.w + eh.w);
        y0.x += p0 * xv.x; y0.y += p0 * xv.y; y0.z += p0 * xv.z; y0.w += p0 * xv.w;
        y1.x += p1 * xv.x; y1.y += p1 * xv.y; y1.z += p1 * xv.z; y1.w += p1 * xv.w;
        y2.x += p2 * xv.x; y2.y += p2 * xv.y; y2.z += p2 * xv.z; y2.w += p2 * xv.w;
        y3.x += p3 * xv.x; y3.y += p3 * xv.y; y3.z += p3 * xv.z; y3.w += p3 * xv.w;
        S0 += p0; S1 += p1; S2 += p2; S3 += p3;
    }
    // pair-reduce (lanes 2nl, 2nl+1 adjacent in wave)
    y0.x += __shfl_xor(y0.x, 1); y0.y += __shfl_xor(y0.y, 1);
    y0.z += __shfl_xor(y0.z, 1); y0.w += __shfl_xor(y0.w, 1);
    y1.x += __shfl_xor(y1.x, 1); y1.y += __shfl_xor(y1.y, 1);
    y1.z += __shfl_xor(y1.z, 1); y1.w += __shfl_xor(y1.w, 1);
    y2.x += __shfl_xor(y2.x, 1); y2.y += __shfl_xor(y2.y, 1);
    y2.z += __shfl_xor(y2.z, 1); y2.w += __shfl_xor(y2.w, 1);
    y3.x += __shfl_xor(y3.x, 1); y3.y += __shfl_xor(y3.y, 1);
    y3.z += __shfl_xor(y3.z, 1); y3.w += __shfl_xor(y3.w, 1);
    S0 += __shfl_xor(S0, 1); S1 += __shfl_xor(S1, 1);
    S2 += __shfl_xor(S2, 1); S3 += __shfl_xor(S3, 1);
    if (node < NNODES) {
        float4* ap = (float4*)(acc + (size_t)node * 20);
        float4 sv = {S0, S1, S2, S3};
        if (sub == 0) { ap[0] = y0; ap[2] = y2; ap[4] = sv; }
        else { ap[1] = y1; ap[3] = y3; }
    }
    // per-bin S partial (plain store, reduced inside k_out)
    float z0 = (sub == 0 && node < NNODES) ? S0 : 0.f;
    float z1 = (sub == 0 && node < NNODES) ? S1 : 0.f;
    float z2 = (sub == 0 && node < NNODES) ? S2 : 0.f;
    float z3 = (sub == 0 && node < NNODES) ? S3 : 0.f;
#pragma unroll
    for (int off = 1; off < 64; off <<= 1) {
        z0 += __shfl_xor(z0, off); z1 += __shfl_xor(z1, off);
        z2 += __shfl_xor(z2, off); z3 += __shfl_xor(z3, off);
    }
    int w = t >> 6;
    if ((t & 63) == 0) { sw[w][0] = z0; sw[w][1] = z1; sw[w][2] = z2; sw[w][3] = z3; }
    __syncthreads();
    if (t == 0) {
        float4 v;
        v.x = sw[0][0] + sw[1][0] + sw[2][0] + sw[3][0];
        v.y = sw[0][1] + sw[1][1] + sw[2][1] + sw[3][1];
        v.z = sw[0][2] + sw[1][2] + sw[2][2] + sw[3][2];
        v.w = sw[0][3] + sw[1][3] + sw[2][3] + sw[3][3];
        ((float4*)pS)[bin] = v;
    }
}

// reduce per-bin S partials (in every block, ~0.2us) + normalize + collapsed
// output projection + residual
__global__ __launch_bounds__(256) void k_out(
        const float* __restrict__ acc, const float* __restrict__ pS,
        const float* __restrict__ Wq, const float* __restrict__ bq,
        const float* __restrict__ Wk, const float* __restrict__ bk,
        const float* __restrict__ Wv, const float* __restrict__ bv,
        const float* __restrict__ Wo, const float* __restrict__ bo,
        const float* __restrict__ x, float* __restrict__ out) {
    __shared__ float Cl[192];
    __shared__ float sd[4][4];
    __shared__ float dd[4];
    int t = threadIdx.x;
    compute_C_entry(t, Wq, bq, Wk, bk, Wv, bv, Wo, Cl);
    float s0 = 0.f, s1 = 0.f, s2 = 0.f, s3 = 0.f;
    for (int i = t; i < NBINS; i += 256) {
        float4 v = ((const float4*)pS)[i];
        s0 += v.x; s1 += v.y; s2 += v.z; s3 += v.w;
    }
#pragma unroll
    for (int off = 1; off < 64; off <<= 1) {
        s0 += __shfl_xor(s0, off); s1 += __shfl_xor(s1, off);
        s2 += __shfl_xor(s2, off); s3 += __shfl_xor(s3, off);
    }
    int w = t >> 6;
    if ((t & 63) == 0) { sd[w][0] = s0; sd[w][1] = s1; sd[w][2] = s2; sd[w][3] = s3; }
    __syncthreads();
    if (t < 4) dd[t] = 1.f / (sd[0][t] + sd[1][t] + sd[2][t] + sd[3][t]);
    __syncthreads();
    int i = blockIdx.x * blockDim.x + t;
    if (i >= NNODES) return;
    const float4* ap = (const float4*)(acc + (size_t)i * 20);
    float4 y[4] = {ap[0], ap[1], ap[2], ap[3]};
    float4 S = ap[4];
    float Sv[4] = {S.x, S.y, S.z, S.w};
    float di[4] = {dd[0], dd[1], dd[2], dd[3]};
    float o[4];
#pragma unroll
    for (int oo = 0; oo < 4; oo++) {
        float a = bo[oo];
#pragma unroll
        for (int h = 0; h < 4; h++) {
            float m = Cl[100 + h * 16 + oo * 4 + 0] * y[h].x
                    + Cl[100 + h * 16 + oo * 4 + 1] * y[h].y
                    + Cl[100 + h * 16 + oo * 4 + 2] * y[h].z
                    + Cl[100 + h * 16 + oo * 4 + 3] * y[h].w
                    + Cl[164 + h * 4 + oo] * Sv[h];
            a += di[h] * m;
        }
        o[oo] = a;
    }
    float4 xv = ((const float4*)x)[i];
    float4 ov;
    ov.x = o[0] + xv.x; ov.y = o[1] + xv.y; ov.z = o[2] + xv.z; ov.w = o[3] + xv.w;
    ((float4*)out)[i] = ov;
}

extern "C" void kernel_launch(void* const* d_in, const int* in_sizes, int n_in,
                              void* d_out, int out_size, void* d_ws, size_t ws_size,
                              hipStream_t stream) {
    const float* x = (const float*)d_in[0];
    const int* ei = (const int*)d_in[1];
    const float* Wq = (const float*)d_in[2];
    const float* bq = (const float*)d_in[3];
    const float* Wk = (const float*)d_in[4];
    const float* bk = (const float*)d_in[5];
    const float* Wv = (const float*)d_in[6];
    const float* bv = (const float*)d_in[7];
    const float* Wo = (const float*)d_in[8];
    const float* bo = (const float*)d_in[9];
    float* out = (float*)d_out;

    float* fws = (float*)d_ws;
    float* acc = fws;                                 // NNODES*20 f32, 4 MB
    float* pS = acc + (size_t)NNODES * 20;            // NBINS*4 f32
    unsigned* binned = (unsigned*)(pS + (size_t)NBINS * 4 + 4);  // NBINS*NBLK*FCAP u32, 25 MB

    k_binA<<<NBLK, 256, 0, stream>>>(ei, binned);
    k_accum<<<NBINS, 256, 0, stream>>>(binned, x, Wq, bq, Wk, bk, Wv, bv, Wo, acc, pS);
    k_out<<<(NNODES + 255) / 256, 256, 0, stream>>>(acc, pS,
                                                    Wq, bq, Wk, bk, Wv, bv, Wo, bo, x, out);
}

// Round 11
// 55.318 us; speedup vs baseline: 1.2350x; 1.2350x over previous
//
#include <hip/hip_runtime.h>
#include <math.h>

#define NNODES 50000
#define NEDGES 1600000
#define BINSZ 128                  // nodes per bin (bin = c >> 7)
#define NBINS 391                  // ceil(50000/128)
#define NBLK 1000                  // sorter blocks
#define EPB (NEDGES / NBLK)        // 1600 edges per chunk
#define BCAP 4608                  // per-bin edge capacity (mean 4092, +8 sigma)
#define SCALE 0.17677669529663687f // 1/sqrt(32)

// Constant table C[] (LDS, 180 floats), built redundantly per block (5.7k MACs):
//   A[h][a][b]  : 0   + h*16 + a*4 + b   (Wq_h^T Wk_h)
//   U[h][b]     : 64  + h*4 + b          (bq_h^T Wk_h)   pairs with x[c]
//   V[h][a]     : 80  + h*4 + a          (Wq_h^T bk_h)   pairs with x[r]
//   W0[h]       : 96  + h                (bq_h . bk_h)
//   M[h][o][a]  : 100 + h*16 + o*4 + a   (Wo[o,hslice] . Wv_h[:,a])
//   N[h][o]     : 164 + h*4 + o          (Wo[o,hslice] . bv_h)
__device__ __forceinline__ void compute_C_entry(int t,
        const float* Wq, const float* bq, const float* Wk, const float* bk,
        const float* Wv, const float* bv, const float* Wo, float* C_lds) {
    if (t < 64) {
        int h = t >> 4, a = (t >> 2) & 3, b = t & 3;
        float s = 0.f;
        for (int k = 0; k < 32; k++) s += Wq[(h * 32 + k) * 4 + a] * Wk[(h * 32 + k) * 4 + b];
        C_lds[t] = s;
    } else if (t < 80) {
        int h = (t - 64) >> 2, b = (t - 64) & 3;
        float s = 0.f;
        for (int k = 0; k < 32; k++) s += bq[h * 32 + k] * Wk[(h * 32 + k) * 4 + b];
        C_lds[t] = s;
    } else if (t < 96) {
        int h = (t - 80) >> 2, a = (t - 80) & 3;
        float s = 0.f;
        for (int k = 0; k < 32; k++) s += Wq[(h * 32 + k) * 4 + a] * bk[h * 32 + k];
        C_lds[t] = s;
    } else if (t < 100) {
        int h = t - 96;
        float s = 0.f;
        for (int k = 0; k < 32; k++) s += bq[h * 32 + k] * bk[h * 32 + k];
        C_lds[t] = s;
    } else if (t < 164) {
        int i = t - 100;
        int h = i >> 4, o = (i >> 2) & 3, a = i & 3;
        float s = 0.f;
        for (int k = 0; k < 32; k++) s += Wo[o * 128 + h * 32 + k] * Wv[(h * 32 + k) * 4 + a];
        C_lds[t] = s;
    } else if (t < 180) {
        int i = t - 164;
        int h = i >> 2, o = i & 3;
        float s = 0.f;
        for (int k = 0; k < 32; k++) s += Wo[o * 128 + h * 32 + k] * bv[h * 32 + k];
        C_lds[t] = s;
    }
}

// LDS counting-sort per 1600-edge chunk -> ONE contiguous 6.4KB chunk write +
// one contiguous 391-entry directory row. Zero scattered global stores.
__global__ __launch_bounds__(256) void k_binA(const int* __restrict__ ei,
                                              unsigned* __restrict__ chunks,
                                              unsigned* __restrict__ dir) {
    __shared__ unsigned raw[EPB];
    __shared__ unsigned srt[EPB];
    __shared__ int h0[512];
    __shared__ int h1[512];
    int t = threadIdx.x, blk = blockIdx.x;
    for (int i = t; i < 512; i += 256) h0[i] = 0;
    __syncthreads();
    int e0 = blk * EPB;
    for (int i = t; i < EPB; i += 256) {
        int r = ei[e0 + i];
        int c = ei[NEDGES + e0 + i];
        raw[i] = ((unsigned)c << 16) | (unsigned)r;
        atomicAdd(&h0[c >> 7], 1);
    }
    __syncthreads();
    // inclusive Hillis-Steele scan over 512 (double-buffered)
    int* src = h0; int* dst = h1;
    for (int off = 1; off < 512; off <<= 1) {
        for (int i = t; i < 512; i += 256)
            dst[i] = src[i] + (i >= off ? src[i - off] : 0);
        __syncthreads();
        int* tmp = src; src = dst; dst = tmp;
    }
    // dst (free buffer) becomes insert pointers = exclusive scan
    for (int i = t; i < 512; i += 256) dst[i] = i ? src[i - 1] : 0;
    __syncthreads();
    for (int i = t; i < EPB; i += 256) {
        unsigned v = raw[i];
        int b = v >> 23;                    // (c>>7)
        int pos = atomicAdd(&dst[b], 1);
        srt[pos] = v;
    }
    __syncthreads();
    uint4* co = (uint4*)(chunks + (size_t)blk * EPB);
    const uint4* si = (const uint4*)srt;
    for (int i = t; i < EPB / 4; i += 256) co[i] = si[i];
    for (int b = t; b < NBINS; b += 256) {
        int start = b ? src[b - 1] : 0;
        int len = src[b] - start;
        dir[(size_t)blk * NBINS + b] = ((unsigned)start << 16) | (unsigned)len;
    }
}

// One block per 128-node bin: directory-driven gather of the bin's runs from
// all 1000 chunks, LDS compaction + counting-sort by local node (int LDS
// atomics only), then 2 lanes/node accumulate y_h/S_h in registers.
__global__ __launch_bounds__(256) void k_accum(
        const unsigned* __restrict__ chunks, const unsigned* __restrict__ dir,
        const float* __restrict__ x,
        const float* __restrict__ Wq, const float* __restrict__ bq,
        const float* __restrict__ Wk, const float* __restrict__ bk,
        const float* __restrict__ Wv, const float* __restrict__ bv,
        const float* __restrict__ Wo,
        float* __restrict__ acc, float* __restrict__ pS) {
    __shared__ float Cl[192];
    __shared__ float pe[BINSZ][20];
    __shared__ unsigned raw[BCAP];
    __shared__ unsigned short srt[BCAP];
    __shared__ int hist[BINSZ];
    __shared__ int ofs[BINSZ];
    __shared__ int nv;
    __shared__ float sw[4][4];
    int bin = blockIdx.x;
    int t = threadIdx.x;
    int base = bin << 7;
    compute_C_entry(t, Wq, bq, Wk, bk, Wv, bv, Wo, Cl);
    if (t < BINSZ) hist[t] = 0;
    if (t == 0) nv = 0;
    __syncthreads();
    // per-node score coefficients g[16], e[4]
    if (t < BINSZ) {
        int node = base + t;
        if (node < NNODES) {
            float4 xv = ((const float4*)x)[node];
            float pr[20];
#pragma unroll
            for (int h = 0; h < 4; h++) {
#pragma unroll
                for (int a = 0; a < 4; a++) {
                    float g = Cl[80 + h * 4 + a]
                            + Cl[h * 16 + a * 4 + 0] * xv.x + Cl[h * 16 + a * 4 + 1] * xv.y
                            + Cl[h * 16 + a * 4 + 2] * xv.z + Cl[h * 16 + a * 4 + 3] * xv.w;
                    pr[h * 4 + a] = g * SCALE;
                }
                float e = Cl[96 + h]
                        + Cl[64 + h * 4 + 0] * xv.x + Cl[64 + h * 4 + 1] * xv.y
                        + Cl[64 + h * 4 + 2] * xv.z + Cl[64 + h * 4 + 3] * xv.w;
                pr[16 + h] = e * SCALE;
            }
#pragma unroll
            for (int q = 0; q < 5; q++) ((float4*)pe[t])[q] = ((const float4*)pr)[q];
        }
    }
    // gather this bin's run from every chunk (runs are contiguous; L2-resident)
    for (int blk = t; blk < NBLK; blk += 256) {
        unsigned d = dir[(size_t)blk * NBINS + bin];
        int start = d >> 16;
        int len = d & 0xFFFFu;
        const unsigned* cp = chunks + (size_t)blk * EPB + start;
        for (int j = 0; j < len; j++) {
            unsigned v = cp[j];
            int pos = atomicAdd(&nv, 1);
            if (pos < BCAP) {
                raw[pos] = v;
                atomicAdd(&hist[(int)(v >> 16) - base], 1);
            }
        }
    }
    __syncthreads();
    // exclusive prefix over 128 counters (wave 0, 2 counters/lane)
    if (t < 64) {
        int a0 = hist[2 * t], a1 = hist[2 * t + 1];
        int pair = a0 + a1;
        int p = pair;
#pragma unroll
        for (int off = 1; off < 64; off <<= 1) {
            int u = __shfl_up(p, off, 64);
            if (t >= off) p += u;
        }
        int excl = p - pair;
        hist[2 * t] = excl; hist[2 * t + 1] = excl + a0;
        ofs[2 * t] = excl;  ofs[2 * t + 1] = excl + a0;
    }
    __syncthreads();
    int nval = nv < BCAP ? nv : BCAP;
    for (int i = t; i < nval; i += 256) {
        unsigned v = raw[i];
        int lc = (int)(v >> 16) - base;
        int pos = atomicAdd(&ofs[lc], 1);
        srt[pos] = (unsigned short)(v & 0xFFFFu);
    }
    __syncthreads();
    // accumulate: 2 lanes per node, registers only
    int nl = t >> 1;
    int sub = t & 1;
    int node = base + nl;
    int sBeg = hist[nl], sEnd = ofs[nl];
    float4 g0 = ((const float4*)pe[nl])[0];
    float4 g1 = ((const float4*)pe[nl])[1];
    float4 g2 = ((const float4*)pe[nl])[2];
    float4 g3 = ((const float4*)pe[nl])[3];
    float4 eh = ((const float4*)pe[nl])[4];
    float S0 = 0.f, S1 = 0.f, S2 = 0.f, S3 = 0.f;
    float4 y0 = {0, 0, 0, 0}, y1 = y0, y2 = y0, y3 = y0;
    for (int i = sBeg + sub; i < sEnd; i += 2) {
        int r = (int)srt[i];
        float4 xv = ((const float4*)x)[r];
        float p0 = __expf(xv.x * g0.x + xv.y * g0.y + xv.z * g0.z + xv.w * g0.w + eh.x);
        float p1 = __expf(xv.x * g1.x + xv.y * g1.y + xv.z * g1.z + xv.w * g1.w + eh.y);
        float p2 = __expf(xv.x * g2.x + xv.y * g2.y + xv.z * g2.z + xv.w * g2.w + eh.z);
        float p3 = __expf(xv.x * g3.x + xv.y * g3.y + xv.z * g3.z + xv.w * g3.w + eh.w);
        y0.x += p0 * xv.x; y0.y += p0 * xv.y; y0.z += p0 * xv.z; y0.w += p0 * xv.w;
        y1.x += p1 * xv.x; y1.y += p1 * xv.y; y1.z += p1 * xv.z; y1.w += p1 * xv.w;
        y2.x += p2 * xv.x; y2.y += p2 * xv.y; y2.z += p2 * xv.z; y2.w += p2 * xv.w;
        y3.x += p3 * xv.x; y3.y += p3 * xv.y; y3.z += p3 * xv.z; y3.w += p3 * xv.w;
        S0 += p0; S1 += p1; S2 += p2; S3 += p3;
    }
    // pair-reduce (lanes 2nl, 2nl+1 adjacent)
    y0.x += __shfl_xor(y0.x, 1); y0.y += __shfl_xor(y0.y, 1);
    y0.z += __shfl_xor(y0.z, 1); y0.w += __shfl_xor(y0.w, 1);
    y1.x += __shfl_xor(y1.x, 1); y1.y += __shfl_xor(y1.y, 1);
    y1.z += __shfl_xor(y1.z, 1); y1.w += __shfl_xor(y1.w, 1);
    y2.x += __shfl_xor(y2.x, 1); y2.y += __shfl_xor(y2.y, 1);
    y2.z += __shfl_xor(y2.z, 1); y2.w += __shfl_xor(y2.w, 1);
    y3.x += __shfl_xor(y3.x, 1); y3.y += __shfl_xor(y3.y, 1);
    y3.z += __shfl_xor(y3.z, 1); y3.w += __shfl_xor(y3.w, 1);
    S0 += __shfl_xor(S0, 1); S1 += __shfl_xor(S1, 1);
    S2 += __shfl_xor(S2, 1); S3 += __shfl_xor(S3, 1);
    if (node < NNODES) {
        float4* ap = (float4*)(acc + (size_t)node * 20);
        float4 sv = {S0, S1, S2, S3};
        if (sub == 0) { ap[0] = y0; ap[2] = y2; ap[4] = sv; }
        else { ap[1] = y1; ap[3] = y3; }
    }
    // per-bin S partial (plain store, reduced inside k_out)
    float z0 = (sub == 0 && node < NNODES) ? S0 : 0.f;
    float z1 = (sub == 0 && node < NNODES) ? S1 : 0.f;
    float z2 = (sub == 0 && node < NNODES) ? S2 : 0.f;
    float z3 = (sub == 0 && node < NNODES) ? S3 : 0.f;
#pragma unroll
    for (int off = 1; off < 64; off <<= 1) {
        z0 += __shfl_xor(z0, off); z1 += __shfl_xor(z1, off);
        z2 += __shfl_xor(z2, off); z3 += __shfl_xor(z3, off);
    }
    int w = t >> 6;
    if ((t & 63) == 0) { sw[w][0] = z0; sw[w][1] = z1; sw[w][2] = z2; sw[w][3] = z3; }
    __syncthreads();
    if (t == 0) {
        float4 v;
        v.x = sw[0][0] + sw[1][0] + sw[2][0] + sw[3][0];
        v.y = sw[0][1] + sw[1][1] + sw[2][1] + sw[3][1];
        v.z = sw[0][2] + sw[1][2] + sw[2][2] + sw[3][2];
        v.w = sw[0][3] + sw[1][3] + sw[2][3] + sw[3][3];
        ((float4*)pS)[bin] = v;
    }
}

// reduce per-bin S partials + normalize + collapsed output projection + residual
__global__ __launch_bounds__(256) void k_out(
        const float* __restrict__ acc, const float* __restrict__ pS,
        const float* __restrict__ Wq, const float* __restrict__ bq,
        const float* __restrict__ Wk, const float* __restrict__ bk,
        const float* __restrict__ Wv, const float* __restrict__ bv,
        const float* __restrict__ Wo, const float* __restrict__ bo,
        const float* __restrict__ x, float* __restrict__ out) {
    __shared__ float Cl[192];
    __shared__ float sd[4][4];
    __shared__ float dd[4];
    int t = threadIdx.x;
    compute_C_entry(t, Wq, bq, Wk, bk, Wv, bv, Wo, Cl);
    float s0 = 0.f, s1 = 0.f, s2 = 0.f, s3 = 0.f;
    for (int i = t; i < NBINS; i += 256) {
        float4 v = ((const float4*)pS)[i];
        s0 += v.x; s1 += v.y; s2 += v.z; s3 += v.w;
    }
#pragma unroll
    for (int off = 1; off < 64; off <<= 1) {
        s0 += __shfl_xor(s0, off); s1 += __shfl_xor(s1, off);
        s2 += __shfl_xor(s2, off); s3 += __shfl_xor(s3, off);
    }
    int w = t >> 6;
    if ((t & 63) == 0) { sd[w][0] = s0; sd[w][1] = s1; sd[w][2] = s2; sd[w][3] = s3; }
    __syncthreads();
    if (t < 4) dd[t] = 1.f / (sd[0][t] + sd[1][t] + sd[2][t] + sd[3][t]);
    __syncthreads();
    int i = blockIdx.x * blockDim.x + t;
    if (i >= NNODES) return;
    const float4* ap = (const float4*)(acc + (size_t)i * 20);
    float4 y[4] = {ap[0], ap[1], ap[2], ap[3]};
    float4 S = ap[4];
    float Sv[4] = {S.x, S.y, S.z, S.w};
    float di[4] = {dd[0], dd[1], dd[2], dd[3]};
    float o[4];
#pragma unroll
    for (int oo = 0; oo < 4; oo++) {
        float a = bo[oo];
#pragma unroll
        for (int h = 0; h < 4; h++) {
            float m = Cl[100 + h * 16 + oo * 4 + 0] * y[h].x
                    + Cl[100 + h * 16 + oo * 4 + 1] * y[h].y
                    + Cl[100 + h * 16 + oo * 4 + 2] * y[h].z
                    + Cl[100 + h * 16 + oo * 4 + 3] * y[h].w
                    + Cl[164 + h * 4 + oo] * Sv[h];
            a += di[h] * m;
        }
        o[oo] = a;
    }
    float4 xv = ((const float4*)x)[i];
    float4 ov;
    ov.x = o[0] + xv.x; ov.y = o[1] + xv.y; ov.z = o[2] + xv.z; ov.w = o[3] + xv.w;
    ((float4*)out)[i] = ov;
}

extern "C" void kernel_launch(void* const* d_in, const int* in_sizes, int n_in,
                              void* d_out, int out_size, void* d_ws, size_t ws_size,
                              hipStream_t stream) {
    const float* x = (const float*)d_in[0];
    const int* ei = (const int*)d_in[1];
    const float* Wq = (const float*)d_in[2];
    const float* bq = (const float*)d_in[3];
    const float* Wk = (const float*)d_in[4];
    const float* bk = (const float*)d_in[5];
    const float* Wv = (const float*)d_in[6];
    const float* bv = (const float*)d_in[7];
    const float* Wo = (const float*)d_in[8];
    const float* bo = (const float*)d_in[9];
    float* out = (float*)d_out;

    float* fws = (float*)d_ws;
    float* acc = fws;                                  // NNODES*20 f32, 4 MB
    float* pS = acc + (size_t)NNODES * 20;             // NBINS*4 f32
    unsigned* chunks = (unsigned*)(pS + (size_t)NBINS * 4 + 4);  // NEDGES u32, 6.4 MB
    unsigned* dir = chunks + (size_t)NEDGES;           // NBLK*NBINS u32, 1.56 MB

    k_binA<<<NBLK, 256, 0, stream>>>(ei, chunks, dir);
    k_accum<<<NBINS, 256, 0, stream>>>(chunks, dir, x, Wq, bq, Wk, bk, Wv, bv, Wo, acc, pS);
    k_out<<<(NNODES + 255) / 256, 256, 0, stream>>>(acc, pS,
                                                    Wq, bq, Wk, bk, Wv, bv, Wo, bo, x, out);
}

// Round 12
// 51.421 us; speedup vs baseline: 1.3286x; 1.0758x over previous
//
#include <hip/hip_runtime.h>
#include <math.h>

#define NNODES 50000
#define NEDGES 1600000
#define BINSZ 128                  // nodes per bin (bin = c >> 7)
#define NBINS 391                  // ceil(50000/128)
#define NBLK 1000                  // sorter blocks
#define EPB (NEDGES / NBLK)        // 1600 edges per chunk
#define HALF 500                   // chunks per accum part
#define PCAP 2560                  // per-(bin,part) edge capacity (mean 2046, +11 sigma)
#define SCALE 0.17677669529663687f // 1/sqrt(32)

// Constant table C[] (LDS, 180 floats), built redundantly per block (5.7k MACs):
//   A[h][a][b]  : 0   + h*16 + a*4 + b   (Wq_h^T Wk_h)
//   U[h][b]     : 64  + h*4 + b          (bq_h^T Wk_h)   pairs with x[c]
//   V[h][a]     : 80  + h*4 + a          (Wq_h^T bk_h)   pairs with x[r]
//   W0[h]       : 96  + h                (bq_h . bk_h)
//   M[h][o][a]  : 100 + h*16 + o*4 + a   (Wo[o,hslice] . Wv_h[:,a])
//   N[h][o]     : 164 + h*4 + o          (Wo[o,hslice] . bv_h)
__device__ __forceinline__ void compute_C_entry(int t,
        const float* Wq, const float* bq, const float* Wk, const float* bk,
        const float* Wv, const float* bv, const float* Wo, float* C_lds) {
    if (t < 64) {
        int h = t >> 4, a = (t >> 2) & 3, b = t & 3;
        float s = 0.f;
        for (int k = 0; k < 32; k++) s += Wq[(h * 32 + k) * 4 + a] * Wk[(h * 32 + k) * 4 + b];
        C_lds[t] = s;
    } else if (t < 80) {
        int h = (t - 64) >> 2, b = (t - 64) & 3;
        float s = 0.f;
        for (int k = 0; k < 32; k++) s += bq[h * 32 + k] * Wk[(h * 32 + k) * 4 + b];
        C_lds[t] = s;
    } else if (t < 96) {
        int h = (t - 80) >> 2, a = (t - 80) & 3;
        float s = 0.f;
        for (int k = 0; k < 32; k++) s += Wq[(h * 32 + k) * 4 + a] * bk[h * 32 + k];
        C_lds[t] = s;
    } else if (t < 100) {
        int h = t - 96;
        float s = 0.f;
        for (int k = 0; k < 32; k++) s += bq[h * 32 + k] * bk[h * 32 + k];
        C_lds[t] = s;
    } else if (t < 164) {
        int i = t - 100;
        int h = i >> 4, o = (i >> 2) & 3, a = i & 3;
        float s = 0.f;
        for (int k = 0; k < 32; k++) s += Wo[o * 128 + h * 32 + k] * Wv[(h * 32 + k) * 4 + a];
        C_lds[t] = s;
    } else if (t < 180) {
        int i = t - 164;
        int h = i >> 2, o = i & 3;
        float s = 0.f;
        for (int k = 0; k < 32; k++) s += Wo[o * 128 + h * 32 + k] * bv[h * 32 + k];
        C_lds[t] = s;
    }
}

// LDS counting-sort per 1600-edge chunk -> contiguous 6.4KB chunk write + one
// contiguous directory row. Scan done by a single wave (shfl), 2 barriers.
__global__ __launch_bounds__(256) void k_binA(const int* __restrict__ ei,
                                              unsigned* __restrict__ chunks,
                                              unsigned* __restrict__ dir) {
    __shared__ unsigned raw[EPB];
    __shared__ unsigned srt[EPB];
    __shared__ int hist[512];   // counts -> exclusive starts
    __shared__ int ofs[512];    // insert pointers -> ends
    int t = threadIdx.x, blk = blockIdx.x;
    hist[t] = 0; hist[t + 256] = 0;
    __syncthreads();
    int e0 = blk * EPB;
    for (int i = t; i < EPB; i += 256) {
        int r = ei[e0 + i];
        int c = ei[NEDGES + e0 + i];
        raw[i] = ((unsigned)c << 16) | (unsigned)r;
        atomicAdd(&hist[c >> 7], 1);
    }
    __syncthreads();
    // single-wave scan over 512 counters: lane L owns bins [8L, 8L+8)
    if (t < 64) {
        int v[8], run = 0;
#pragma unroll
        for (int j = 0; j < 8; j++) { v[j] = hist[8 * t + j]; run += v[j]; }
        int p = run;
#pragma unroll
        for (int off = 1; off < 64; off <<= 1) {
            int u = __shfl_up(p, off, 64);
            if (t >= off) p += u;
        }
        int base = p - run;  // exclusive prefix of this lane's group
#pragma unroll
        for (int j = 0; j < 8; j++) {
            hist[8 * t + j] = base;   // start
            ofs[8 * t + j] = base;    // insert pointer
            base += v[j];
        }
    }
    __syncthreads();
    for (int i = t; i < EPB; i += 256) {
        unsigned v = raw[i];
        int pos = atomicAdd(&ofs[v >> 23], 1);
        srt[pos] = v;
    }
    __syncthreads();
    uint4* co = (uint4*)(chunks + (size_t)blk * EPB);
    const uint4* si = (const uint4*)srt;
    for (int i = t; i < EPB / 4; i += 256) co[i] = si[i];
    for (int b = t; b < NBINS; b += 256) {
        int start = hist[b];
        int len = ofs[b] - start;
        dir[(size_t)blk * NBINS + b] = ((unsigned)start << 16) | (unsigned)len;
    }
}

// 782 blocks: bin = bid>>1 owns nodes [bin*128,..), part = bid&1 owns chunks
// [part*500, part*500+500). Atomic-free compaction via block-scan of per-thread
// run lengths; counting-sort; 2 lanes/node register accumulation.
__global__ __launch_bounds__(256) void k_accum(
        const unsigned* __restrict__ chunks, const unsigned* __restrict__ dir,
        const float* __restrict__ x,
        const float* __restrict__ Wq, const float* __restrict__ bq,
        const float* __restrict__ Wk, const float* __restrict__ bk,
        const float* __restrict__ Wv, const float* __restrict__ bv,
        const float* __restrict__ Wo,
        float* __restrict__ acc, float* __restrict__ pS) {
    __shared__ float Cl[192];
    __shared__ float pe[BINSZ][20];
    __shared__ unsigned raw[PCAP];
    __shared__ unsigned short srt[PCAP];
    __shared__ int hist[BINSZ];
    __shared__ int ofs[BINSZ];
    __shared__ int wsum[4];
    __shared__ float sw[4][4];
    int bid = blockIdx.x;
    int bin = bid >> 1;
    int part = bid & 1;
    int t = threadIdx.x;
    int base = bin << 7;
    compute_C_entry(t, Wq, bq, Wk, bk, Wv, bv, Wo, Cl);
    if (t < BINSZ) hist[t] = 0;
    __syncthreads();
    // per-node score coefficients g[16], e[4]
    if (t < BINSZ) {
        int node = base + t;
        if (node < NNODES) {
            float4 xv = ((const float4*)x)[node];
            float pr[20];
#pragma unroll
            for (int h = 0; h < 4; h++) {
#pragma unroll
                for (int a = 0; a < 4; a++) {
                    float g = Cl[80 + h * 4 + a]
                            + Cl[h * 16 + a * 4 + 0] * xv.x + Cl[h * 16 + a * 4 + 1] * xv.y
                            + Cl[h * 16 + a * 4 + 2] * xv.z + Cl[h * 16 + a * 4 + 3] * xv.w;
                    pr[h * 4 + a] = g * SCALE;
                }
                float e = Cl[96 + h]
                        + Cl[64 + h * 4 + 0] * xv.x + Cl[64 + h * 4 + 1] * xv.y
                        + Cl[64 + h * 4 + 2] * xv.z + Cl[64 + h * 4 + 3] * xv.w;
                pr[16 + h] = e * SCALE;
            }
#pragma unroll
            for (int q = 0; q < 5; q++) ((float4*)pe[t])[q] = ((const float4*)pr)[q];
        }
    }
    // directory entries for this thread (chunks part*500 + {t, t+256})
    int blk0 = part * HALF + t;
    int blk1 = part * HALF + t + 256;
    unsigned d0 = 0, d1 = 0;
    int cnt = 0;
    if (t < HALF) { d0 = dir[(size_t)blk0 * NBINS + bin]; cnt += d0 & 0xFFFFu; }
    if (t + 256 < HALF) { d1 = dir[(size_t)blk1 * NBINS + bin]; cnt += d1 & 0xFFFFu; }
    // block-scan of cnt -> exact raw[] destinations (no same-address atomics)
    int lane = t & 63, w = t >> 6;
    int p = cnt;
#pragma unroll
    for (int off = 1; off < 64; off <<= 1) {
        int u = __shfl_up(p, off, 64);
        if (lane >= off) p += u;
    }
    if (lane == 63) wsum[w] = p;
    __syncthreads();
    int wbase = 0;
#pragma unroll
    for (int ww = 0; ww < 4; ww++) wbase += (ww < w) ? wsum[ww] : 0;
    int off0 = wbase + p - cnt;
    int nval = wsum[0] + wsum[1] + wsum[2] + wsum[3];
    if (nval > PCAP) nval = PCAP;
    // copy runs to raw + histogram by local node (scattered LDS atomics only)
    if (t < HALF) {
        int len = d0 & 0xFFFFu;
        const unsigned* cp = chunks + (size_t)blk0 * EPB + (d0 >> 16);
        for (int j = 0; j < len; j++) {
            unsigned v = cp[j];
            if (off0 < PCAP) raw[off0] = v;
            atomicAdd(&hist[(int)(v >> 16) - base], 1);
            off0++;
        }
    }
    if (t + 256 < HALF) {
        int len = d1 & 0xFFFFu;
        const unsigned* cp = chunks + (size_t)blk1 * EPB + (d1 >> 16);
        for (int j = 0; j < len; j++) {
            unsigned v = cp[j];
            if (off0 < PCAP) raw[off0] = v;
            atomicAdd(&hist[(int)(v >> 16) - base], 1);
            off0++;
        }
    }
    __syncthreads();
    // single-wave exclusive prefix over 128 counters (lane owns 2 bins)
    if (t < 64) {
        int a0 = hist[2 * t], a1 = hist[2 * t + 1];
        int pair = a0 + a1;
        int pp = pair;
#pragma unroll
        for (int off = 1; off < 64; off <<= 1) {
            int u = __shfl_up(pp, off, 64);
            if (t >= off) pp += u;
        }
        int excl = pp - pair;
        hist[2 * t] = excl; hist[2 * t + 1] = excl + a0;
        ofs[2 * t] = excl;  ofs[2 * t + 1] = excl + a0;
    }
    __syncthreads();
    // scatter into per-node contiguous segments (scattered 128-address atomics)
    for (int i = t; i < nval; i += 256) {
        unsigned v = raw[i];
        int lc = (int)(v >> 16) - base;
        int pos = atomicAdd(&ofs[lc], 1);
        srt[pos] = (unsigned short)(v & 0xFFFFu);
    }
    __syncthreads();
    // accumulate: 2 lanes per node, registers only
    int nl = t >> 1;
    int sub = t & 1;
    int node = base + nl;
    int sBeg = hist[nl], sEnd = ofs[nl];
    float4 g0 = ((const float4*)pe[nl])[0];
    float4 g1 = ((const float4*)pe[nl])[1];
    float4 g2 = ((const float4*)pe[nl])[2];
    float4 g3 = ((const float4*)pe[nl])[3];
    float4 eh = ((const float4*)pe[nl])[4];
    float S0 = 0.f, S1 = 0.f, S2 = 0.f, S3 = 0.f;
    float4 y0 = {0, 0, 0, 0}, y1 = y0, y2 = y0, y3 = y0;
    for (int i = sBeg + sub; i < sEnd; i += 2) {
        int r = (int)srt[i];
        float4 xv = ((const float4*)x)[r];
        float p0 = __expf(xv.x * g0.x + xv.y * g0.y + xv.z * g0.z + xv.w * g0.w + eh.x);
        float p1 = __expf(xv.x * g1.x + xv.y * g1.y + xv.z * g1.z + xv.w * g1.w + eh.y);
        float p2 = __expf(xv.x * g2.x + xv.y * g2.y + xv.z * g2.z + xv.w * g2.w + eh.z);
        float p3 = __expf(xv.x * g3.x + xv.y * g3.y + xv.z * g3.z + xv.w * g3.w + eh.w);
        y0.x += p0 * xv.x; y0.y += p0 * xv.y; y0.z += p0 * xv.z; y0.w += p0 * xv.w;
        y1.x += p1 * xv.x; y1.y += p1 * xv.y; y1.z += p1 * xv.z; y1.w += p1 * xv.w;
        y2.x += p2 * xv.x; y2.y += p2 * xv.y; y2.z += p2 * xv.z; y2.w += p2 * xv.w;
        y3.x += p3 * xv.x; y3.y += p3 * xv.y; y3.z += p3 * xv.z; y3.w += p3 * xv.w;
        S0 += p0; S1 += p1; S2 += p2; S3 += p3;
    }
    y0.x += __shfl_xor(y0.x, 1); y0.y += __shfl_xor(y0.y, 1);
    y0.z += __shfl_xor(y0.z, 1); y0.w += __shfl_xor(y0.w, 1);
    y1.x += __shfl_xor(y1.x, 1); y1.y += __shfl_xor(y1.y, 1);
    y1.z += __shfl_xor(y1.z, 1); y1.w += __shfl_xor(y1.w, 1);
    y2.x += __shfl_xor(y2.x, 1); y2.y += __shfl_xor(y2.y, 1);
    y2.z += __shfl_xor(y2.z, 1); y2.w += __shfl_xor(y2.w, 1);
    y3.x += __shfl_xor(y3.x, 1); y3.y += __shfl_xor(y3.y, 1);
    y3.z += __shfl_xor(y3.z, 1); y3.w += __shfl_xor(y3.w, 1);
    S0 += __shfl_xor(S0, 1); S1 += __shfl_xor(S1, 1);
    S2 += __shfl_xor(S2, 1); S3 += __shfl_xor(S3, 1);
    if (node < NNODES) {
        float4* ap = (float4*)(acc + ((size_t)part * NNODES + node) * 20);
        float4 sv = {S0, S1, S2, S3};
        if (sub == 0) { ap[0] = y0; ap[2] = y2; ap[4] = sv; }
        else { ap[1] = y1; ap[3] = y3; }
    }
    // per-block S partial (plain store, reduced inside k_out)
    float z0 = (sub == 0 && node < NNODES) ? S0 : 0.f;
    float z1 = (sub == 0 && node < NNODES) ? S1 : 0.f;
    float z2 = (sub == 0 && node < NNODES) ? S2 : 0.f;
    float z3 = (sub == 0 && node < NNODES) ? S3 : 0.f;
#pragma unroll
    for (int off = 1; off < 64; off <<= 1) {
        z0 += __shfl_xor(z0, off); z1 += __shfl_xor(z1, off);
        z2 += __shfl_xor(z2, off); z3 += __shfl_xor(z3, off);
    }
    if ((t & 63) == 0) { sw[w][0] = z0; sw[w][1] = z1; sw[w][2] = z2; sw[w][3] = z3; }
    __syncthreads();
    if (t == 0) {
        float4 v;
        v.x = sw[0][0] + sw[1][0] + sw[2][0] + sw[3][0];
        v.y = sw[0][1] + sw[1][1] + sw[2][1] + sw[3][1];
        v.z = sw[0][2] + sw[1][2] + sw[2][2] + sw[3][2];
        v.w = sw[0][3] + sw[1][3] + sw[2][3] + sw[3][3];
        ((float4*)pS)[bid] = v;
    }
}

// reduce per-block S partials + sum part accumulators + normalize + collapsed
// output projection + residual
__global__ __launch_bounds__(256) void k_out(
        const float* __restrict__ acc, const float* __restrict__ pS,
        const float* __restrict__ Wq, const float* __restrict__ bq,
        const float* __restrict__ Wk, const float* __restrict__ bk,
        const float* __restrict__ Wv, const float* __restrict__ bv,
        const float* __restrict__ Wo, const float* __restrict__ bo,
        const float* __restrict__ x, float* __restrict__ out) {
    __shared__ float Cl[192];
    __shared__ float sd[4][4];
    __shared__ float dd[4];
    int t = threadIdx.x;
    compute_C_entry(t, Wq, bq, Wk, bk, Wv, bv, Wo, Cl);
    float s0 = 0.f, s1 = 0.f, s2 = 0.f, s3 = 0.f;
    for (int i = t; i < 2 * NBINS; i += 256) {
        float4 v = ((const float4*)pS)[i];
        s0 += v.x; s1 += v.y; s2 += v.z; s3 += v.w;
    }
#pragma unroll
    for (int off = 1; off < 64; off <<= 1) {
        s0 += __shfl_xor(s0, off); s1 += __shfl_xor(s1, off);
        s2 += __shfl_xor(s2, off); s3 += __shfl_xor(s3, off);
    }
    int w = t >> 6;
    if ((t & 63) == 0) { sd[w][0] = s0; sd[w][1] = s1; sd[w][2] = s2; sd[w][3] = s3; }
    __syncthreads();
    if (t < 4) dd[t] = 1.f / (sd[0][t] + sd[1][t] + sd[2][t] + sd[3][t]);
    __syncthreads();
    int i = blockIdx.x * blockDim.x + t;
    if (i >= NNODES) return;
    const float4* a0 = (const float4*)(acc + (size_t)i * 20);
    const float4* a1 = (const float4*)(acc + ((size_t)NNODES + i) * 20);
    float4 y[4], S;
#pragma unroll
    for (int q = 0; q < 4; q++) {
        float4 u = a0[q], v = a1[q];
        y[q].x = u.x + v.x; y[q].y = u.y + v.y; y[q].z = u.z + v.z; y[q].w = u.w + v.w;
    }
    {
        float4 u = a0[4], v = a1[4];
        S.x = u.x + v.x; S.y = u.y + v.y; S.z = u.z + v.z; S.w = u.w + v.w;
    }
    float Sv[4] = {S.x, S.y, S.z, S.w};
    float di[4] = {dd[0], dd[1], dd[2], dd[3]};
    float o[4];
#pragma unroll
    for (int oo = 0; oo < 4; oo++) {
        float a = bo[oo];
#pragma unroll
        for (int h = 0; h < 4; h++) {
            float m = Cl[100 + h * 16 + oo * 4 + 0] * y[h].x
                    + Cl[100 + h * 16 + oo * 4 + 1] * y[h].y
                    + Cl[100 + h * 16 + oo * 4 + 2] * y[h].z
                    + Cl[100 + h * 16 + oo * 4 + 3] * y[h].w
                    + Cl[164 + h * 4 + oo] * Sv[h];
            a += di[h] * m;
        }
        o[oo] = a;
    }
    float4 xv = ((const float4*)x)[i];
    float4 ov;
    ov.x = o[0] + xv.x; ov.y = o[1] + xv.y; ov.z = o[2] + xv.z; ov.w = o[3] + xv.w;
    ((float4*)out)[i] = ov;
}

extern "C" void kernel_launch(void* const* d_in, const int* in_sizes, int n_in,
                              void* d_out, int out_size, void* d_ws, size_t ws_size,
                              hipStream_t stream) {
    const float* x = (const float*)d_in[0];
    const int* ei = (const int*)d_in[1];
    const float* Wq = (const float*)d_in[2];
    const float* bq = (const float*)d_in[3];
    const float* Wk = (const float*)d_in[4];
    const float* bk = (const float*)d_in[5];
    const float* Wv = (const float*)d_in[6];
    const float* bv = (const float*)d_in[7];
    const float* Wo = (const float*)d_in[8];
    const float* bo = (const float*)d_in[9];
    float* out = (float*)d_out;

    float* fws = (float*)d_ws;
    float* acc = fws;                                   // 2*NNODES*20 f32, 8 MB
    float* pS = acc + (size_t)2 * NNODES * 20;          // 2*NBINS*4 f32
    unsigned* chunks = (unsigned*)(pS + (size_t)2 * NBINS * 4 + 4);  // NEDGES u32
    unsigned* dir = chunks + (size_t)NEDGES;            // NBLK*NBINS u32

    k_binA<<<NBLK, 256, 0, stream>>>(ei, chunks, dir);
    k_accum<<<2 * NBINS, 256, 0, stream>>>(chunks, dir, x, Wq, bq, Wk, bk, Wv, bv, Wo, acc, pS);
    k_out<<<(NNODES + 255) / 256, 256, 0, stream>>>(acc, pS,
                                                    Wq, bq, Wk, bk, Wv, bv, Wo, bo, x, out);
}